// Round 5
// baseline (1834.077 us; speedup 1.0000x reference)
//
#include <hip/hip_runtime.h>
#include <math.h>

constexpr int Bb = 4, Nn = 2048, Dd = 2048, Ee = 8, Cbn = 512;
constexpr int Mm = Bb * Nn;          // 8192 tokens

typedef _Float16 half8 __attribute__((ext_vector_type(8)));
typedef float floatx16 __attribute__((ext_vector_type(16)));

#define GLL16(g, l)                                                     \
  __builtin_amdgcn_global_load_lds(                                     \
      (const __attribute__((address_space(1))) void*)(g),               \
      (__attribute__((address_space(3))) void*)(l), 16, 0, 0)

#define MFMA_F16(a, b, c) __builtin_amdgcn_mfma_f32_32x32x16_f16(a, b, c, 0, 0, 0)

// Operand layout (A and B sides), 8 KB per (128-tile, kt16):
//   [tile128][kt16(128)][hl(2)][chunk(2)][row(128)][8 f16]
// k within kt16 = chunk*8 + j -> matches mfma A/B lane layout (k = (lane>>5)*8+j).
// Linear GLL16 copy of a slab gives conflict-free ds_read_b128 fragments
// (32 consecutive rows x 16B = contiguous 512B per half-wave).

// ---------------- fused prep: transpose+split W, split X --------------------
__global__ __launch_bounds__(256) void prep_kernel(const float* __restrict__ W,
                                                   _Float16* __restrict__ WT,
                                                   const float* __restrict__ X,
                                                   _Float16* __restrict__ XT) {
  __shared__ _Float16 thi[64][72];
  __shared__ _Float16 tlo[64][72];
  const int bid = blockIdx.x;
  if (bid < 2048) {
    // ---- transpose + hi/lo split W: [E,D,C] f32 -> tiled f16
    const int kt = bid & 31;         // 64 d's each
    const int ct = (bid >> 5) & 7;   // 64 c's each
    const int e = bid >> 8;
    const int tx = threadIdx.x & 15, ty = threadIdx.x >> 4;
    const float* src = W + ((size_t)(e * 2048 + kt * 64)) * 512 + ct * 64;
#pragma unroll
    for (int p = 0; p < 4; ++p) {
      int kk = ty + p * 16;
      float4 v = *(const float4*)(src + (size_t)kk * 512 + tx * 4);
      _Float16 hh;
      hh = (_Float16)v.x; thi[tx * 4 + 0][kk] = hh; tlo[tx * 4 + 0][kk] = (_Float16)(v.x - (float)hh);
      hh = (_Float16)v.y; thi[tx * 4 + 1][kk] = hh; tlo[tx * 4 + 1][kk] = (_Float16)(v.y - (float)hh);
      hh = (_Float16)v.z; thi[tx * 4 + 2][kk] = hh; tlo[tx * 4 + 2][kk] = (_Float16)(v.z - (float)hh);
      hh = (_Float16)v.w; thi[tx * 4 + 3][kk] = hh; tlo[tx * 4 + 3][kk] = (_Float16)(v.w - (float)hh);
    }
    __syncthreads();
    const int nt = e * 4 + (ct >> 1);  // 128-col tile index, 0..31
#pragma unroll
    for (int p = 0; p < 2; ++p) {
      int unit = threadIdx.x + p * 256;  // 0..511
      int ch = unit >> 6;                // 0..7 (8 d's each)
      int cc = unit & 63;
      int kt16 = kt * 4 + (ch >> 1);
      int chunk = ch & 1;
      int row = (ct & 1) * 64 + cc;
      _Float16* dst = WT + ((size_t)(nt * 128 + kt16)) * 4096 + chunk * 1024 + row * 8;
      *(half8*)dst = *(const half8*)(&thi[cc][ch * 8]);
      *(half8*)(dst + 2048) = *(const half8*)(&tlo[cc][ch * 8]);
    }
  } else {
    // ---- hi/lo split X: [M,D] f32 -> tiled f16
    const int id = bid - 2048;
    const int mt = id & 63;   // 128-row tile
    const int kb = id >> 6;   // 32-k block
    const int tid = threadIdx.x;
#pragma unroll
    for (int p = 0; p < 2; ++p) {
      const int u = tid + p * 256;  // 0..511
      const int c4 = u & 3;
      const int row = u >> 2;
      const float* src = X + ((size_t)(mt * 128 + row)) * 2048 + kb * 32 + c4 * 8;
      float4 a = *(const float4*)src;
      float4 b = *(const float4*)(src + 4);
      float f[8] = {a.x, a.y, a.z, a.w, b.x, b.y, b.z, b.w};
      half8 hi, lo;
#pragma unroll
      for (int j = 0; j < 8; ++j) {
        _Float16 hh = (_Float16)f[j];
        hi[j] = hh;
        lo[j] = (_Float16)(f[j] - (float)hh);
      }
      const int kt16 = kb * 2 + (c4 >> 1);
      const int chunk = c4 & 1;
      _Float16* dst = XT + ((size_t)(mt * 128 + kt16)) * 4096 + chunk * 1024 + row * 8;
      *(half8*)dst = hi;
      *(half8*)(dst + 2048) = lo;
    }
  }
}

// ---------------- MFMA GEMM: 256x256 tile, 4 quadrants x 2-way K-split ------
// 8 waves: wave w owns quadrant qp=w&3 (128x128) and k16-half ks=w>>2.
// Per wave per BK=32 slot: 16 ds_read_b128 -> 48 MFMA (vs r4's 24->48).
// Epilogue: ks=1 publishes acc via LDS, ks=0 adds, then sum-of-squares.
__global__ __launch_bounds__(512) void gemm_mfma(const _Float16* __restrict__ XT,
                                                 const _Float16* __restrict__ WT,
                                                 float* __restrict__ partial) {
  // XCD-aware swizzle (512 blocks, 512%8==0 -> simple bijection)
  const int bid = blockIdx.x;
  const int swz = (bid & 7) * 64 + (bid >> 3);
  const int bM = swz >> 4;  // 0..31 (256 rows)
  const int bN = swz & 15;  // 0..15 (256 cols)

  const int tid = threadIdx.x;
  const int w = tid >> 6, l = tid & 63;
  const int qp = w & 3, qm = qp >> 1, qn = qp & 1, ks = w >> 2;
  const int h = l >> 5, l31 = l & 31;

  // 2 slots x (A 32KB | B 32KB) = 128 KB; one slot = BK=32 (two kt16 units)
  __shared__ __align__(16) char lds[131072];

  // ---- staging: 8 GLL16/wave/slot (4 A + 4 B); LDS image = linear slab copy
  // slot layout: [ht(2)][k16(2)][hl(2)][chunk(2)][row(128)][16B]
  const char* XTb = (const char*)XT;
  const char* WTb = (const char*)WT;
  const char* srcA[4];
  const char* srcB[4];
  int ldsAo[4], ldsBo[4];
#pragma unroll
  for (int q = 0; q < 4; ++q) {
    const int c = q * 8 + w;  // 1KB chunk index 0..31
    const int ht = c >> 4, k16 = (c >> 3) & 1, u = c & 7;
    srcA[q] = XTb + (size_t)(bM * 2 + ht) * 1048576 + k16 * 8192 + u * 1024 + l * 16;
    srcB[q] = WTb + (size_t)(bN * 2 + ht) * 1048576 + k16 * 8192 + u * 1024 + l * 16;
    ldsAo[q] = c * 1024;            // wave-uniform; HW adds lane*16
    ldsBo[q] = 32768 + c * 1024;
  }

  // ---- fragment read offsets (within a slot); this wave reads only k16=ks
  int aoff[4][2], boff[4][2];  // [mf|nf][hl]
#pragma unroll
  for (int mf = 0; mf < 4; ++mf)
#pragma unroll
    for (int hl = 0; hl < 2; ++hl)
      aoff[mf][hl] = qm * 16384 + ks * 8192 + hl * 4096 + h * 2048 +
                     (mf * 32 + l31) * 16;
#pragma unroll
  for (int nf = 0; nf < 4; ++nf)
#pragma unroll
    for (int hl = 0; hl < 2; ++hl)
      boff[nf][hl] = 32768 + qn * 16384 + ks * 8192 + hl * 4096 + h * 2048 +
                     (nf * 32 + l31) * 16;

  floatx16 acc[4][4] = {};

  auto stage = [&](int t) {
    const size_t ko = (size_t)t * 16384;
    char* base = lds + (t & 1) * 65536;
#pragma unroll
    for (int q = 0; q < 4; ++q) {
      GLL16(srcA[q] + ko, base + ldsAo[q]);
      GLL16(srcB[q] + ko, base + ldsBo[q]);
    }
  };
  auto compute = [&](int t) {
    const char* Lb = lds + (t & 1) * 65536;
    half8 ah[4], al[4];
#pragma unroll
    for (int mf = 0; mf < 4; ++mf) {
      ah[mf] = *(const half8*)(Lb + aoff[mf][0]);
      al[mf] = *(const half8*)(Lb + aoff[mf][1]);
    }
#pragma unroll
    for (int hn = 0; hn < 2; ++hn) {
      half8 bh[2], bl[2];
#pragma unroll
      for (int j = 0; j < 2; ++j) {
        bh[j] = *(const half8*)(Lb + boff[hn * 2 + j][0]);
        bl[j] = *(const half8*)(Lb + boff[hn * 2 + j][1]);
      }
      __builtin_amdgcn_s_setprio(1);
#pragma unroll
      for (int mf = 0; mf < 4; ++mf)
#pragma unroll
        for (int j = 0; j < 2; ++j) {
          const int nf = hn * 2 + j;
          acc[mf][nf] = MFMA_F16(ah[mf], bh[j], acc[mf][nf]);
          acc[mf][nf] = MFMA_F16(ah[mf], bl[j], acc[mf][nf]);
          acc[mf][nf] = MFMA_F16(al[mf], bh[j], acc[mf][nf]);
        }
      __builtin_amdgcn_s_setprio(0);
    }
  };

  // ---- prologue
  stage(0);
  asm volatile("s_waitcnt vmcnt(0)" ::: "memory");
  __builtin_amdgcn_s_barrier();

  // ---- main: stage next slot, compute current, drain (issued ~3000cy ago)
  for (int kt = 0; kt < 63; ++kt) {
    stage(kt + 1);
    compute(kt);
    asm volatile("s_waitcnt vmcnt(0)" ::: "memory");
    __builtin_amdgcn_s_barrier();
  }
  compute(63);  // reads slot 1; epilogue below reuses slot-0 area only

  // ---- cross-wave K-reduction: ks=1 publishes, ks=0 accumulates ------------
#pragma unroll
  for (int mf = 0; mf < 4; ++mf) {
    if (ks == 1) {
#pragma unroll
      for (int nf = 0; nf < 4; ++nf)
#pragma unroll
        for (int rg = 0; rg < 4; ++rg) {
          float4 v = make_float4(acc[mf][nf][rg * 4 + 0], acc[mf][nf][rg * 4 + 1],
                                 acc[mf][nf][rg * 4 + 2], acc[mf][nf][rg * 4 + 3]);
          *(float4*)(lds + qp * 16384 + nf * 4096 + rg * 1024 + l * 16) = v;
        }
    }
    __syncthreads();
    if (ks == 0) {
#pragma unroll
      for (int nf = 0; nf < 4; ++nf)
#pragma unroll
        for (int rg = 0; rg < 4; ++rg) {
          float4 v = *(const float4*)(lds + qp * 16384 + nf * 4096 + rg * 1024 + l * 16);
          acc[mf][nf][rg * 4 + 0] += v.x;
          acc[mf][nf][rg * 4 + 1] += v.y;
          acc[mf][nf][rg * 4 + 2] += v.z;
          acc[mf][nf][rg * 4 + 3] += v.w;
        }
    }
    __syncthreads();
  }

  // ---- epilogue (ks=0 waves): per-row sum of squares, 64-col slices --------
  if (ks == 0) {
#pragma unroll
    for (int mf = 0; mf < 4; ++mf)
#pragma unroll
      for (int g = 0; g < 2; ++g) {
        float mv = 0.f;
#pragma unroll
        for (int reg = 0; reg < 16; ++reg) {
          float v = acc[mf][g * 2][reg] * acc[mf][g * 2][reg] +
                    acc[mf][g * 2 + 1][reg] * acc[mf][g * 2 + 1][reg];
#pragma unroll
          for (int m = 1; m <= 16; m <<= 1) v += __shfl_xor(v, m, 64);
          if (l31 == reg) mv = v;
        }
        if (l31 < 16) {
          const int rowin = (l31 & 3) + 8 * (l31 >> 2) + 4 * h;
          const int tok = bM * 256 + qm * 128 + mf * 32 + rowin;
          const int slice = bN * 4 + qn * 2 + g;  // n/64 index, 0..63
          partial[(size_t)tok * 64 + slice] = mv;
        }
      }
  }
}

// ---------------- fused softmax/top-2 + per-batch capacity scan -------------
__global__ __launch_bounds__(1024) void route_scan(const float* __restrict__ partial,
                                                   int* __restrict__ idx1,
                                                   int* __restrict__ idx2,
                                                   float* __restrict__ p1,
                                                   float* __restrict__ p2,
                                                   int* __restrict__ prios) {
  const int b = blockIdx.x;   // 0..3
  const int tid = threadIdx.x;
  __shared__ unsigned char e1s[2048], e2s[2048];
  __shared__ int cnts[1024][9];  // +1 pad: conflict-free phase-2 stores

  // phase 1: routing for tokens n = 2*tid, 2*tid+1
#pragma unroll
  for (int r = 0; r < 2; ++r) {
    const int n = tid * 2 + r;
    const int t = b * 2048 + n;
    const float4* pr = (const float4*)(partial + (size_t)t * 64);
    float l[Ee];
    float mx = -1e30f;
#pragma unroll
    for (int e = 0; e < Ee; ++e) {
      float4 s0 = pr[e * 2], s1 = pr[e * 2 + 1];
      float s = s0.x + s0.y + s0.z + s0.w + s1.x + s1.y + s1.z + s1.w;
      l[e] = sqrtf(s);
      mx = fmaxf(mx, l[e]);
    }
    float p[Ee];
    float s = 0.f;
#pragma unroll
    for (int e = 0; e < Ee; ++e) {
      p[e] = expf(l[e] - mx);
      s += p[e];
    }
    float inv = 1.f / s;
    int i1 = 0;
    float b1 = l[0];
#pragma unroll
    for (int e = 1; e < Ee; ++e)
      if (l[e] > b1) { b1 = l[e]; i1 = e; }
    int i2 = -1;
    float b2 = -1e30f;
#pragma unroll
    for (int e = 0; e < Ee; ++e)
      if (e != i1 && l[e] > b2) { b2 = l[e]; i2 = e; }
    idx1[t] = i1;
    idx2[t] = i2;
    p1[t] = p[i1] * inv;
    p2[t] = p[i2] * inv;
    e1s[n] = (unsigned char)i1;
    e2s[n] = (unsigned char)i2;
  }
  __syncthreads();

  // phase 2: local counts for entries p = 4*tid .. 4*tid+3 (p = k*2048+n)
  int cnt[Ee] = {0, 0, 0, 0, 0, 0, 0, 0};
  int eloc[4];
#pragma unroll
  for (int i = 0; i < 4; ++i) {
    const int p = tid * 4 + i;
    const int e = (p >> 11) ? (int)e2s[p & 2047] : (int)e1s[p & 2047];
    eloc[i] = e;
    cnt[e]++;
  }
#pragma unroll
  for (int e = 0; e < Ee; ++e) cnts[tid][e] = cnt[e];
  __syncthreads();

  // phase 3: per-expert exclusive prefix over the 1024 thread-chunks
  const int wv = tid >> 6, ln = tid & 63;
  if (wv < 8) {
    int loc[16];
    int s = 0;
#pragma unroll
    for (int i = 0; i < 16; ++i) {
      loc[i] = cnts[ln * 16 + i][wv];
      s += loc[i];
    }
    int x = s;
#pragma unroll
    for (int off = 1; off < 64; off <<= 1) {
      int y = __shfl_up(x, off, 64);
      if (ln >= off) x += y;
    }
    int run = x - s;  // exclusive prefix of this lane's 16-chunk
#pragma unroll
    for (int i = 0; i < 16; ++i) {
      int tmp = loc[i];
      cnts[ln * 16 + i][wv] = run;
      run += tmp;
    }
  }
  __syncthreads();

  // phase 4: assign priorities in order
  int base[Ee];
#pragma unroll
  for (int e = 0; e < Ee; ++e) base[e] = cnts[tid][e];
#pragma unroll
  for (int i = 0; i < 4; ++i) {
    prios[b * 4096 + tid * 4 + i] = base[eloc[i]]++;
  }
}

// ---------------- branchless single-pass zero+scatter (one block/token) -----
__global__ __launch_bounds__(256) void zscatter_kernel(const int* __restrict__ idx1,
                                                       const int* __restrict__ idx2,
                                                       const float* __restrict__ p1,
                                                       const float* __restrict__ p2,
                                                       const int* __restrict__ prios,
                                                       float* __restrict__ out, int cap) {
  const int t = blockIdx.x;       // token 0..Mm-1
  const int ec = Ee * cap;        // 5120
  const int b = t >> 11;
  const int n = t & (Nn - 1);
  const int e1 = idx1[t], e2 = idx2[t];
  const int q1 = prios[b * 2 * Nn + n];
  const int q2 = prios[b * 2 * Nn + Nn + n];
  const float v1 = p1[t], v2 = p2[t];
  const int d1 = (q1 < cap) ? e1 * cap + q1 : -1;
  const int d2 = (q2 < cap) ? e2 * cap + q2 : -1;
  float4* o1 = (float4*)(out + (size_t)t * ec);             // dispatch slice
  float4* o2 = (float4*)(out + (size_t)(Mm + t) * ec);      // combine slice
  const int n4 = ec / 4;  // 1280
  for (int i = threadIdx.x; i < n4; i += 256) {
    const int base = i * 4;
    float4 dv, cv;
    dv.x = (d1 == base + 0 || d2 == base + 0) ? 1.f : 0.f;
    dv.y = (d1 == base + 1 || d2 == base + 1) ? 1.f : 0.f;
    dv.z = (d1 == base + 2 || d2 == base + 2) ? 1.f : 0.f;
    dv.w = (d1 == base + 3 || d2 == base + 3) ? 1.f : 0.f;
    cv.x = (d1 == base + 0) ? v1 : ((d2 == base + 0) ? v2 : 0.f);
    cv.y = (d1 == base + 1) ? v1 : ((d2 == base + 1) ? v2 : 0.f);
    cv.z = (d1 == base + 2) ? v1 : ((d2 == base + 2) ? v2 : 0.f);
    cv.w = (d1 == base + 3) ? v1 : ((d2 == base + 3) ? v2 : 0.f);
    o1[i] = dv;
    o2[i] = cv;
  }
}

extern "C" void kernel_launch(void* const* d_in, const int* in_sizes, int n_in,
                              void* d_out, int out_size, void* d_ws, size_t ws_size,
                              hipStream_t stream) {
  const float* X = (const float*)d_in[0];
  const float* W = (const float*)d_in[1];
  float* out = (float*)d_out;
  const int cap = out_size / (2 * Bb * Nn * Ee);  // 640

  char* ws = (char*)d_ws;
  _Float16* WT = (_Float16*)ws;                    // 32 MB tiled hi/lo W^T
  float* partial = (float*)(ws + 33554432ull);     // Mm*64 f32 = 2 MB
  int* idx1 = (int*)(ws + 35651584ull);
  int* idx2 = idx1 + Mm;
  float* p1 = (float*)(idx2 + Mm);
  float* p2 = p1 + Mm;
  int* prios = (int*)(p2 + Mm);

  // XT (64 MB, tiled hi/lo X) lives in d_out as scratch: consumed by gemm_mfma
  // and then fully overwritten by zscatter_kernel (stream-ordered).
  _Float16* XT = (_Float16*)d_out;

  prep_kernel<<<6144, 256, 0, stream>>>(W, WT, X, XT);
  gemm_mfma<<<512, 512, 0, stream>>>(XT, WT, partial);
  route_scan<<<Bb, 1024, 0, stream>>>(partial, idx1, idx2, p1, p2, prios);
  zscatter_kernel<<<Mm, 256, 0, stream>>>(idx1, idx2, p1, p2, prios, out, cap);
}

// Round 6
// 785.970 us; speedup vs baseline: 2.3335x; 2.3335x over previous
//
#include <hip/hip_runtime.h>
#include <math.h>

constexpr int Bb = 4, Nn = 2048, Dd = 2048, Ee = 8, Cbn = 512;
constexpr int Mm = Bb * Nn;          // 8192 tokens

typedef _Float16 half8 __attribute__((ext_vector_type(8)));
typedef float floatx16 __attribute__((ext_vector_type(16)));

#define GLL16(g, l)                                                     \
  __builtin_amdgcn_global_load_lds(                                     \
      (const __attribute__((address_space(1))) void*)(g),               \
      (__attribute__((address_space(3))) void*)(l), 16, 0, 0)

#define MFMA_F16(a, b, c) __builtin_amdgcn_mfma_f32_32x32x16_f16(a, b, c, 0, 0, 0)

// Operand layout (A and B sides), 8 KB per (128-tile, kt16):
//   [tile128][kt16(128)][hl(2)][chunk(2)][row(128)][8 f16]
// k within kt16 = chunk*8 + j -> matches mfma A/B lane layout (k = (lane>>5)*8+j).
// A is consumed straight from global (fragment-ordered, 512B segments/load);
// B goes through LDS (shared by all 8 waves), linear GLL16 slab copy.

// ---------------- fused prep: transpose+split W, split X --------------------
__global__ __launch_bounds__(256) void prep_kernel(const float* __restrict__ W,
                                                   _Float16* __restrict__ WT,
                                                   const float* __restrict__ X,
                                                   _Float16* __restrict__ XT) {
  __shared__ _Float16 thi[64][72];
  __shared__ _Float16 tlo[64][72];
  const int bid = blockIdx.x;
  if (bid < 2048) {
    // ---- transpose + hi/lo split W: [E,D,C] f32 -> tiled f16
    const int kt = bid & 31;         // 64 d's each
    const int ct = (bid >> 5) & 7;   // 64 c's each
    const int e = bid >> 8;
    const int tx = threadIdx.x & 15, ty = threadIdx.x >> 4;
    const float* src = W + ((size_t)(e * 2048 + kt * 64)) * 512 + ct * 64;
#pragma unroll
    for (int p = 0; p < 4; ++p) {
      int kk = ty + p * 16;
      float4 v = *(const float4*)(src + (size_t)kk * 512 + tx * 4);
      _Float16 hh;
      hh = (_Float16)v.x; thi[tx * 4 + 0][kk] = hh; tlo[tx * 4 + 0][kk] = (_Float16)(v.x - (float)hh);
      hh = (_Float16)v.y; thi[tx * 4 + 1][kk] = hh; tlo[tx * 4 + 1][kk] = (_Float16)(v.y - (float)hh);
      hh = (_Float16)v.z; thi[tx * 4 + 2][kk] = hh; tlo[tx * 4 + 2][kk] = (_Float16)(v.z - (float)hh);
      hh = (_Float16)v.w; thi[tx * 4 + 3][kk] = hh; tlo[tx * 4 + 3][kk] = (_Float16)(v.w - (float)hh);
    }
    __syncthreads();
    const int nt = e * 4 + (ct >> 1);  // 128-col tile index, 0..31
#pragma unroll
    for (int p = 0; p < 2; ++p) {
      int unit = threadIdx.x + p * 256;  // 0..511
      int ch = unit >> 6;                // 0..7 (8 d's each)
      int cc = unit & 63;
      int kt16 = kt * 4 + (ch >> 1);
      int chunk = ch & 1;
      int row = (ct & 1) * 64 + cc;
      _Float16* dst = WT + ((size_t)(nt * 128 + kt16)) * 4096 + chunk * 1024 + row * 8;
      *(half8*)dst = *(const half8*)(&thi[cc][ch * 8]);
      *(half8*)(dst + 2048) = *(const half8*)(&tlo[cc][ch * 8]);
    }
  } else {
    // ---- hi/lo split X: [M,D] f32 -> tiled f16
    const int id = bid - 2048;
    const int mt = id & 63;   // 128-row tile
    const int kb = id >> 6;   // 32-k block
    const int tid = threadIdx.x;
#pragma unroll
    for (int p = 0; p < 2; ++p) {
      const int u = tid + p * 256;  // 0..511
      const int c4 = u & 3;
      const int row = u >> 2;
      const float* src = X + ((size_t)(mt * 128 + row)) * 2048 + kb * 32 + c4 * 8;
      float4 a = *(const float4*)src;
      float4 b = *(const float4*)(src + 4);
      float f[8] = {a.x, a.y, a.z, a.w, b.x, b.y, b.z, b.w};
      half8 hi, lo;
#pragma unroll
      for (int j = 0; j < 8; ++j) {
        _Float16 hh = (_Float16)f[j];
        hi[j] = hh;
        lo[j] = (_Float16)(f[j] - (float)hh);
      }
      const int kt16 = kb * 2 + (c4 >> 1);
      const int chunk = c4 & 1;
      _Float16* dst = XT + ((size_t)(mt * 128 + kt16)) * 4096 + chunk * 1024 + row * 8;
      *(half8*)dst = hi;
      *(half8*)(dst + 2048) = lo;
    }
  }
}

// ---------------- MFMA GEMM: 256x256 tile, A reg-direct, B via LDS ----------
// 8 waves = 4 wm x 2 wn; wave tile 64 rows x 128 cols; BK=16 slots, ring-2.
// A fragments loaded global->VGPR (XT is fragment-ordered: coalesced 512B).
// B staged to LDS (2 GLL16/wave/slot), frag reads conflict-free 512B runs.
__global__ __launch_bounds__(512) void gemm_mfma(const _Float16* __restrict__ XT,
                                                 const _Float16* __restrict__ WT,
                                                 float* __restrict__ partial) {
  // XCD-aware swizzle (512 blocks, 512%8==0 -> simple bijection)
  const int bid = blockIdx.x;
  const int swz = (bid & 7) * 64 + (bid >> 3);
  const int bM = swz >> 4;  // 0..31 (256 rows)
  const int bN = swz & 15;  // 0..15 (256 cols)

  const int tid = threadIdx.x;
  const int w = tid >> 6, l = tid & 63;
  const int wm = w >> 1, wn = w & 1;  // wave tile: 64 rows x 128 cols
  const int h = l >> 5, l31 = l & 31;

  // 2 slots x 16KB (B only)
  __shared__ __align__(16) char lds[32768];

  const char* XTb = (const char*)XT;
  const char* WTb = (const char*)WT;

  // ---- B staging: 2 GLL16/wave/slot; slot = [ht(2)][hl(2)][chunk(2)][half(2)]
  const char* srcB[2];
  int ldsBo[2];
#pragma unroll
  for (int q = 0; q < 2; ++q) {
    const int c = q * 8 + w;  // 1KB chunk index 0..15
    const int ht = c >> 3, hl = (c >> 2) & 1, ck = (c >> 1) & 1, hf = c & 1;
    srcB[q] = WTb + (size_t)(bN * 2 + ht) * 1048576 + hl * 4096 + ck * 2048 +
              hf * 1024 + l * 16;
    ldsBo[q] = c * 1024;  // wave-uniform; HW adds lane*16
  }

  // ---- A fragment global pointers: frag (mf, hl), rows wm*64+mf*32+l31
  const char* srcA[2][2];
#pragma unroll
  for (int mf = 0; mf < 2; ++mf)
#pragma unroll
    for (int hl = 0; hl < 2; ++hl)
      srcA[mf][hl] = XTb + (size_t)(bM * 2 + (wm >> 1)) * 1048576 + hl * 4096 +
                     h * 2048 + ((wm & 1) * 64 + mf * 32 + l31) * 16;

  // ---- B fragment read offsets within a slot, cols wn*128+nf*32+l31
  int boff[4][2];
#pragma unroll
  for (int nf = 0; nf < 4; ++nf)
#pragma unroll
    for (int hl = 0; hl < 2; ++hl) {
      const int cb = wn * 128 + nf * 32;
      boff[nf][hl] = (cb >> 7) * 8192 + hl * 4096 + h * 2048 + ((cb & 127) + l31) * 16;
    }

  floatx16 acc[2][4] = {};
  half8 aH[2], aL[2];

  auto stageB = [&](int t) {
    const size_t ko = (size_t)t * 8192;
    char* base = lds + (t & 1) * 16384;
#pragma unroll
    for (int q = 0; q < 2; ++q) GLL16(srcB[q] + ko, base + ldsBo[q]);
  };
  auto loadA = [&](int t) {
    const size_t ko = (size_t)t * 8192;
#pragma unroll
    for (int mf = 0; mf < 2; ++mf) {
      aH[mf] = *(const half8*)(srcA[mf][0] + ko);
      aL[mf] = *(const half8*)(srcA[mf][1] + ko);
    }
  };
  auto compute = [&](int t) {
    const char* Lb = lds + (t & 1) * 16384;
    half8 bh[4], bl[4];
#pragma unroll
    for (int nf = 0; nf < 4; ++nf) {
      bh[nf] = *(const half8*)(Lb + boff[nf][0]);
      bl[nf] = *(const half8*)(Lb + boff[nf][1]);
    }
    __builtin_amdgcn_s_setprio(1);
#pragma unroll
    for (int mf = 0; mf < 2; ++mf)
#pragma unroll
      for (int nf = 0; nf < 4; ++nf) {
        acc[mf][nf] = MFMA_F16(aH[mf], bh[nf], acc[mf][nf]);
        acc[mf][nf] = MFMA_F16(aH[mf], bl[nf], acc[mf][nf]);
        acc[mf][nf] = MFMA_F16(aL[mf], bh[nf], acc[mf][nf]);
      }
    __builtin_amdgcn_s_setprio(0);
  };

  // ---- prologue
  stageB(0);
  loadA(0);
  asm volatile("s_waitcnt vmcnt(4)" ::: "memory");  // B GLLs (oldest) done
  __builtin_amdgcn_s_barrier();

  // ---- main loop: 128 BK=16 slots
  for (int t = 0; t < 127; ++t) {
    stageB(t + 1);
    compute(t);      // consumes aH/aL(t) + B slot t
    loadA(t + 1);    // after last A use; latency hides under next slot's front
    asm volatile("s_waitcnt vmcnt(4)" ::: "memory");  // B(t+1) landed; A still in flight
    __builtin_amdgcn_s_barrier();
  }
  compute(127);

  // ---- epilogue: per-row sum of squares over 64-col slices ------------------
#pragma unroll
  for (int mf = 0; mf < 2; ++mf)
#pragma unroll
    for (int g = 0; g < 2; ++g) {
      float mv = 0.f;
#pragma unroll
      for (int reg = 0; reg < 16; ++reg) {
        float v = acc[mf][g * 2][reg] * acc[mf][g * 2][reg] +
                  acc[mf][g * 2 + 1][reg] * acc[mf][g * 2 + 1][reg];
#pragma unroll
        for (int m = 1; m <= 16; m <<= 1) v += __shfl_xor(v, m, 64);
        if (l31 == reg) mv = v;
      }
      if (l31 < 16) {
        const int rowin = (l31 & 3) + 8 * (l31 >> 2) + 4 * h;
        const int tok = bM * 256 + wm * 64 + mf * 32 + rowin;
        const int slice = bN * 4 + wn * 2 + g;  // n/64 index, 0..63
        partial[(size_t)tok * 64 + slice] = mv;
      }
    }
}

// ---------------- fused softmax/top-2 + per-batch capacity scan -------------
__global__ __launch_bounds__(1024) void route_scan(const float* __restrict__ partial,
                                                   int* __restrict__ idx1,
                                                   int* __restrict__ idx2,
                                                   float* __restrict__ p1,
                                                   float* __restrict__ p2,
                                                   int* __restrict__ prios) {
  const int b = blockIdx.x;   // 0..3
  const int tid = threadIdx.x;
  __shared__ unsigned char e1s[2048], e2s[2048];
  __shared__ int cnts[1024][9];  // +1 pad: conflict-free phase-2 stores

  // phase 1: routing for tokens n = 2*tid, 2*tid+1
#pragma unroll
  for (int r = 0; r < 2; ++r) {
    const int n = tid * 2 + r;
    const int t = b * 2048 + n;
    const float4* pr = (const float4*)(partial + (size_t)t * 64);
    float l[Ee];
    float mx = -1e30f;
#pragma unroll
    for (int e = 0; e < Ee; ++e) {
      float4 s0 = pr[e * 2], s1 = pr[e * 2 + 1];
      float s = s0.x + s0.y + s0.z + s0.w + s1.x + s1.y + s1.z + s1.w;
      l[e] = sqrtf(s);
      mx = fmaxf(mx, l[e]);
    }
    float p[Ee];
    float s = 0.f;
#pragma unroll
    for (int e = 0; e < Ee; ++e) {
      p[e] = expf(l[e] - mx);
      s += p[e];
    }
    float inv = 1.f / s;
    int i1 = 0;
    float b1 = l[0];
#pragma unroll
    for (int e = 1; e < Ee; ++e)
      if (l[e] > b1) { b1 = l[e]; i1 = e; }
    int i2 = -1;
    float b2 = -1e30f;
#pragma unroll
    for (int e = 0; e < Ee; ++e)
      if (e != i1 && l[e] > b2) { b2 = l[e]; i2 = e; }
    idx1[t] = i1;
    idx2[t] = i2;
    p1[t] = p[i1] * inv;
    p2[t] = p[i2] * inv;
    e1s[n] = (unsigned char)i1;
    e2s[n] = (unsigned char)i2;
  }
  __syncthreads();

  // phase 2: local counts for entries p = 4*tid .. 4*tid+3 (p = k*2048+n)
  int cnt[Ee] = {0, 0, 0, 0, 0, 0, 0, 0};
  int eloc[4];
#pragma unroll
  for (int i = 0; i < 4; ++i) {
    const int p = tid * 4 + i;
    const int e = (p >> 11) ? (int)e2s[p & 2047] : (int)e1s[p & 2047];
    eloc[i] = e;
    cnt[e]++;
  }
#pragma unroll
  for (int e = 0; e < Ee; ++e) cnts[tid][e] = cnt[e];
  __syncthreads();

  // phase 3: per-expert exclusive prefix over the 1024 thread-chunks
  const int wv = tid >> 6, ln = tid & 63;
  if (wv < 8) {
    int loc[16];
    int s = 0;
#pragma unroll
    for (int i = 0; i < 16; ++i) {
      loc[i] = cnts[ln * 16 + i][wv];
      s += loc[i];
    }
    int x = s;
#pragma unroll
    for (int off = 1; off < 64; off <<= 1) {
      int y = __shfl_up(x, off, 64);
      if (ln >= off) x += y;
    }
    int run = x - s;  // exclusive prefix of this lane's 16-chunk
#pragma unroll
    for (int i = 0; i < 16; ++i) {
      int tmp = loc[i];
      cnts[ln * 16 + i][wv] = run;
      run += tmp;
    }
  }
  __syncthreads();

  // phase 4: assign priorities in order
  int base[Ee];
#pragma unroll
  for (int e = 0; e < Ee; ++e) base[e] = cnts[tid][e];
#pragma unroll
  for (int i = 0; i < 4; ++i) {
    prios[b * 4096 + tid * 4 + i] = base[eloc[i]]++;
  }
}

// ---------------- branchless single-pass zero+scatter (one block/token) -----
__global__ __launch_bounds__(256) void zscatter_kernel(const int* __restrict__ idx1,
                                                       const int* __restrict__ idx2,
                                                       const float* __restrict__ p1,
                                                       const float* __restrict__ p2,
                                                       const int* __restrict__ prios,
                                                       float* __restrict__ out, int cap) {
  const int t = blockIdx.x;       // token 0..Mm-1
  const int ec = Ee * cap;        // 5120
  const int b = t >> 11;
  const int n = t & (Nn - 1);
  const int e1 = idx1[t], e2 = idx2[t];
  const int q1 = prios[b * 2 * Nn + n];
  const int q2 = prios[b * 2 * Nn + Nn + n];
  const float v1 = p1[t], v2 = p2[t];
  const int d1 = (q1 < cap) ? e1 * cap + q1 : -1;
  const int d2 = (q2 < cap) ? e2 * cap + q2 : -1;
  float4* o1 = (float4*)(out + (size_t)t * ec);             // dispatch slice
  float4* o2 = (float4*)(out + (size_t)(Mm + t) * ec);      // combine slice
  const int n4 = ec / 4;  // 1280
  for (int i = threadIdx.x; i < n4; i += 256) {
    const int base = i * 4;
    float4 dv, cv;
    dv.x = (d1 == base + 0 || d2 == base + 0) ? 1.f : 0.f;
    dv.y = (d1 == base + 1 || d2 == base + 1) ? 1.f : 0.f;
    dv.z = (d1 == base + 2 || d2 == base + 2) ? 1.f : 0.f;
    dv.w = (d1 == base + 3 || d2 == base + 3) ? 1.f : 0.f;
    cv.x = (d1 == base + 0) ? v1 : ((d2 == base + 0) ? v2 : 0.f);
    cv.y = (d1 == base + 1) ? v1 : ((d2 == base + 1) ? v2 : 0.f);
    cv.z = (d1 == base + 2) ? v1 : ((d2 == base + 2) ? v2 : 0.f);
    cv.w = (d1 == base + 3) ? v1 : ((d2 == base + 3) ? v2 : 0.f);
    o1[i] = dv;
    o2[i] = cv;
  }
}

extern "C" void kernel_launch(void* const* d_in, const int* in_sizes, int n_in,
                              void* d_out, int out_size, void* d_ws, size_t ws_size,
                              hipStream_t stream) {
  const float* X = (const float*)d_in[0];
  const float* W = (const float*)d_in[1];
  float* out = (float*)d_out;
  const int cap = out_size / (2 * Bb * Nn * Ee);  // 640

  char* ws = (char*)d_ws;
  _Float16* WT = (_Float16*)ws;                    // 32 MB tiled hi/lo W^T
  float* partial = (float*)(ws + 33554432ull);     // Mm*64 f32 = 2 MB
  int* idx1 = (int*)(ws + 35651584ull);
  int* idx2 = idx1 + Mm;
  float* p1 = (float*)(idx2 + Mm);
  float* p2 = p1 + Mm;
  int* prios = (int*)(p2 + Mm);

  // XT (64 MB, tiled hi/lo X) lives in d_out as scratch: consumed by gemm_mfma
  // and then fully overwritten by zscatter_kernel (stream-ordered).
  _Float16* XT = (_Float16*)d_out;

  prep_kernel<<<6144, 256, 0, stream>>>(W, WT, X, XT);
  gemm_mfma<<<512, 512, 0, stream>>>(XT, WT, partial);
  route_scan<<<Bb, 1024, 0, stream>>>(partial, idx1, idx2, p1, p2, prios);
  zscatter_kernel<<<Mm, 256, 0, stream>>>(idx1, idx2, p1, p2, prios, out, cap);
}

// Round 10
// 759.528 us; speedup vs baseline: 2.4148x; 1.0348x over previous
//
#include <hip/hip_runtime.h>
#include <math.h>

constexpr int Bb = 4, Nn = 2048, Dd = 2048, Ee = 8, Cbn = 512;
constexpr int Mm = Bb * Nn;          // 8192 tokens

typedef _Float16 half8 __attribute__((ext_vector_type(8)));
typedef float floatx16 __attribute__((ext_vector_type(16)));

#define GLL16(g, l)                                                     \
  __builtin_amdgcn_global_load_lds(                                     \
      (const __attribute__((address_space(1))) void*)(g),               \
      (__attribute__((address_space(3))) void*)(l), 16, 0, 0)

#define MFMA_F16(a, b, c) __builtin_amdgcn_mfma_f32_32x32x16_f16(a, b, c, 0, 0, 0)

// Operand layout (A and B sides), 8 KB per (128-tile, kt16):
//   [tile128][kt16(128)][hl(2)][chunk(2)][row(128)][8 f16]
// k within kt16 = chunk*8 + j -> matches mfma A/B lane layout (k = (lane>>5)*8+j).
// STRIDE NOTE (r7-r9 NaN root cause): one kt16 block is 8192 BYTES. The gemm
// below uses BK=32 slots = 2 kt16 = 16384 B, so its ko = t*16384 is correct
// (64 slots x 16 KB = 1 MB per tile). The failed ring-4 BK=16 variant stepped
// 16384 B per single-kt16 slot -> read kt16=2t, cross-tile/OOB garbage.

// ---------------- fused prep: transpose+split W, split X --------------------
__global__ __launch_bounds__(256) void prep_kernel(const float* __restrict__ W,
                                                   _Float16* __restrict__ WT,
                                                   const float* __restrict__ X,
                                                   _Float16* __restrict__ XT) {
  __shared__ _Float16 thi[64][72];
  __shared__ _Float16 tlo[64][72];
  const int bid = blockIdx.x;
  if (bid < 2048) {
    // ---- transpose + hi/lo split W: [E,D,C] f32 -> tiled f16
    const int kt = bid & 31;         // 64 d's each
    const int ct = (bid >> 5) & 7;   // 64 c's each
    const int e = bid >> 8;
    const int tx = threadIdx.x & 15, ty = threadIdx.x >> 4;
    const float* src = W + ((size_t)(e * 2048 + kt * 64)) * 512 + ct * 64;
#pragma unroll
    for (int p = 0; p < 4; ++p) {
      int kk = ty + p * 16;
      float4 v = *(const float4*)(src + (size_t)kk * 512 + tx * 4);
      _Float16 hh;
      hh = (_Float16)v.x; thi[tx * 4 + 0][kk] = hh; tlo[tx * 4 + 0][kk] = (_Float16)(v.x - (float)hh);
      hh = (_Float16)v.y; thi[tx * 4 + 1][kk] = hh; tlo[tx * 4 + 1][kk] = (_Float16)(v.y - (float)hh);
      hh = (_Float16)v.z; thi[tx * 4 + 2][kk] = hh; tlo[tx * 4 + 2][kk] = (_Float16)(v.z - (float)hh);
      hh = (_Float16)v.w; thi[tx * 4 + 3][kk] = hh; tlo[tx * 4 + 3][kk] = (_Float16)(v.w - (float)hh);
    }
    __syncthreads();
    const int nt = e * 4 + (ct >> 1);  // 128-col tile index, 0..31
#pragma unroll
    for (int p = 0; p < 2; ++p) {
      int unit = threadIdx.x + p * 256;  // 0..511
      int ch = unit >> 6;                // 0..7 (8 d's each)
      int cc = unit & 63;
      int kt16 = kt * 4 + (ch >> 1);
      int chunk = ch & 1;
      int row = (ct & 1) * 64 + cc;
      _Float16* dst = WT + ((size_t)(nt * 128 + kt16)) * 4096 + chunk * 1024 + row * 8;
      *(half8*)dst = *(const half8*)(&thi[cc][ch * 8]);
      *(half8*)(dst + 2048) = *(const half8*)(&tlo[cc][ch * 8]);
    }
  } else {
    // ---- hi/lo split X: [M,D] f32 -> tiled f16
    const int id = bid - 2048;
    const int mt = id & 63;   // 128-row tile
    const int kb = id >> 6;   // 32-k block
    const int tid = threadIdx.x;
#pragma unroll
    for (int p = 0; p < 2; ++p) {
      const int u = tid + p * 256;  // 0..511
      const int c4 = u & 3;
      const int row = u >> 2;
      const float* src = X + ((size_t)(mt * 128 + row)) * 2048 + kb * 32 + c4 * 8;
      float4 a = *(const float4*)src;
      float4 b = *(const float4*)(src + 4);
      float f[8] = {a.x, a.y, a.z, a.w, b.x, b.y, b.z, b.w};
      half8 hi, lo;
#pragma unroll
      for (int j = 0; j < 8; ++j) {
        _Float16 hh = (_Float16)f[j];
        hi[j] = hh;
        lo[j] = (_Float16)(f[j] - (float)hh);
      }
      const int kt16 = kb * 2 + (c4 >> 1);
      const int chunk = c4 & 1;
      _Float16* dst = XT + ((size_t)(mt * 128 + kt16)) * 4096 + chunk * 1024 + row * 8;
      *(half8*)dst = hi;
      *(half8*)(dst + 2048) = lo;
    }
  }
}

// ---------------- MFMA GEMM: 256x256 tile, 8 waves, ring-2 BK=32 ------------
// (r4-verified green: correct 16 KB/slot stride, full-drain handoff)
__global__ __launch_bounds__(512) void gemm_mfma(const _Float16* __restrict__ XT,
                                                 const _Float16* __restrict__ WT,
                                                 float* __restrict__ partial) {
  // XCD-aware swizzle (512 blocks, 512%8==0 -> simple bijection)
  const int bid = blockIdx.x;
  const int swz = (bid & 7) * 64 + (bid >> 3);
  const int bM = swz >> 4;  // 0..31 (256 rows)
  const int bN = swz & 15;  // 0..15 (256 cols)

  const int tid = threadIdx.x;
  const int w = tid >> 6, l = tid & 63;
  const int wm = w >> 2, wn = w & 3;  // wave tile: 128 rows x 64 cols
  const int h = l >> 5, l31 = l & 31;

  // 2 slots x (A 32KB | B 32KB) = 128 KB; one slot = BK=32 (two kt16 units)
  __shared__ __align__(16) char lds[131072];

  // ---- staging: 8 GLL16/wave/slot (4 A + 4 B); LDS image = linear slab copy
  // slot layout: [ht(2)][k16(2)][hl(2)][chunk(2)][row(128)][16B]
  const char* XTb = (const char*)XT;
  const char* WTb = (const char*)WT;
  const char* srcA[4];
  const char* srcB[4];
  int ldsAo[4], ldsBo[4];
#pragma unroll
  for (int q = 0; q < 4; ++q) {
    const int c = q * 8 + w;  // 1KB chunk index 0..31
    const int ht = c >> 4, k16 = (c >> 3) & 1, u = c & 7;
    srcA[q] = XTb + (size_t)(bM * 2 + ht) * 1048576 + k16 * 8192 + u * 1024 + l * 16;
    srcB[q] = WTb + (size_t)(bN * 2 + ht) * 1048576 + k16 * 8192 + u * 1024 + l * 16;
    ldsAo[q] = c * 1024;            // wave-uniform; HW adds lane*16
    ldsBo[q] = 32768 + c * 1024;
  }

  // ---- fragment read offsets (within a slot)
  int aoff[2][4][2], boff[2][2][2];  // [k16][mf|nf][hl]
#pragma unroll
  for (int k16 = 0; k16 < 2; ++k16) {
#pragma unroll
    for (int mf = 0; mf < 4; ++mf)
#pragma unroll
      for (int hl = 0; hl < 2; ++hl)
        aoff[k16][mf][hl] = wm * 16384 + k16 * 8192 + hl * 4096 + h * 2048 +
                            (mf * 32 + l31) * 16;
#pragma unroll
    for (int nf = 0; nf < 2; ++nf)
#pragma unroll
      for (int hl = 0; hl < 2; ++hl)
        boff[k16][nf][hl] = 32768 + (wn >> 1) * 16384 + k16 * 8192 + hl * 4096 + h * 2048 +
                            ((wn & 1) * 64 + nf * 32 + l31) * 16;
  }

  floatx16 acc[4][2] = {};

  auto stage = [&](int t) {
    const size_t ko = (size_t)t * 16384;   // 2 kt16 = 16 KB per slot: correct
    char* base = lds + (t & 1) * 65536;
#pragma unroll
    for (int q = 0; q < 4; ++q) {
      GLL16(srcA[q] + ko, base + ldsAo[q]);
      GLL16(srcB[q] + ko, base + ldsBo[q]);
    }
  };
  auto compute = [&](int t) {
    const char* Lb = lds + (t & 1) * 65536;
#pragma unroll
    for (int k16 = 0; k16 < 2; ++k16) {
      half8 ah[4], al[4], bh[2], bl[2];
#pragma unroll
      for (int mf = 0; mf < 4; ++mf) {
        ah[mf] = *(const half8*)(Lb + aoff[k16][mf][0]);
        al[mf] = *(const half8*)(Lb + aoff[k16][mf][1]);
      }
#pragma unroll
      for (int nf = 0; nf < 2; ++nf) {
        bh[nf] = *(const half8*)(Lb + boff[k16][nf][0]);
        bl[nf] = *(const half8*)(Lb + boff[k16][nf][1]);
      }
      __builtin_amdgcn_s_setprio(1);
#pragma unroll
      for (int mf = 0; mf < 4; ++mf)
#pragma unroll
        for (int nf = 0; nf < 2; ++nf) {
          acc[mf][nf] = MFMA_F16(ah[mf], bh[nf], acc[mf][nf]);
          acc[mf][nf] = MFMA_F16(ah[mf], bl[nf], acc[mf][nf]);
          acc[mf][nf] = MFMA_F16(al[mf], bh[nf], acc[mf][nf]);
        }
      __builtin_amdgcn_s_setprio(0);
    }
  };

  // ---- prologue
  stage(0);
  asm volatile("s_waitcnt vmcnt(0)" ::: "memory");
  __builtin_amdgcn_s_barrier();

  // ---- main: stage next slot, compute current, full drain (issued ~3100cy ago)
  for (int kt = 0; kt < 63; ++kt) {
    stage(kt + 1);
    compute(kt);
    asm volatile("s_waitcnt vmcnt(0)" ::: "memory");
    __builtin_amdgcn_s_barrier();
  }
  compute(63);

  // ---- epilogue: per-row sum of squares over this wave's 64 cols -----------
  const int slice = bN * 4 + wn;  // n/64 index, 0..63
  float out0 = 0.f, out1 = 0.f;
#pragma unroll
  for (int j = 0; j < 2; ++j) {
    float mv = 0.f;
#pragma unroll
    for (int ii = 0; ii < 2; ++ii) {
      const floatx16& c0 = acc[j * 2 + ii][0];
      const floatx16& c1 = acc[j * 2 + ii][1];
#pragma unroll
      for (int reg = 0; reg < 16; ++reg) {
        float v = c0[reg] * c0[reg] + c1[reg] * c1[reg];
#pragma unroll
        for (int m = 1; m <= 16; m <<= 1) v += __shfl_xor(v, m, 64);
        if (l31 == ii * 16 + reg) mv = v;
      }
    }
    if (j == 0) out0 = mv; else out1 = mv;
  }
  {
    const int reg = l & 15;
    const int ii = l31 >> 4;
    const int rowin = (reg & 3) + 8 * (reg >> 2) + 4 * h;
    const int tok = bM * 256 + wm * 128 + ii * 32 + rowin;
    partial[(size_t)tok * 64 + slice] = out0;
    partial[(size_t)(tok + 64) * 64 + slice] = out1;
  }
}

// ---------------- fused softmax/top-2 + per-batch capacity scan -------------
__global__ __launch_bounds__(1024) void route_scan(const float* __restrict__ partial,
                                                   int* __restrict__ idx1,
                                                   int* __restrict__ idx2,
                                                   float* __restrict__ p1,
                                                   float* __restrict__ p2,
                                                   int* __restrict__ prios) {
  const int b = blockIdx.x;   // 0..3
  const int tid = threadIdx.x;
  __shared__ unsigned char e1s[2048], e2s[2048];
  __shared__ int cnts[1024][9];  // +1 pad: conflict-free phase-2 stores

  // phase 1: routing for tokens n = 2*tid, 2*tid+1
#pragma unroll
  for (int r = 0; r < 2; ++r) {
    const int n = tid * 2 + r;
    const int t = b * 2048 + n;
    const float4* pr = (const float4*)(partial + (size_t)t * 64);
    float l[Ee];
    float mx = -1e30f;
#pragma unroll
    for (int e = 0; e < Ee; ++e) {
      float4 s0 = pr[e * 2], s1 = pr[e * 2 + 1];
      float s = s0.x + s0.y + s0.z + s0.w + s1.x + s1.y + s1.z + s1.w;
      l[e] = sqrtf(s);
      mx = fmaxf(mx, l[e]);
    }
    float p[Ee];
    float s = 0.f;
#pragma unroll
    for (int e = 0; e < Ee; ++e) {
      p[e] = expf(l[e] - mx);
      s += p[e];
    }
    float inv = 1.f / s;
    int i1 = 0;
    float b1 = l[0];
#pragma unroll
    for (int e = 1; e < Ee; ++e)
      if (l[e] > b1) { b1 = l[e]; i1 = e; }
    int i2 = -1;
    float b2 = -1e30f;
#pragma unroll
    for (int e = 0; e < Ee; ++e)
      if (e != i1 && l[e] > b2) { b2 = l[e]; i2 = e; }
    idx1[t] = i1;
    idx2[t] = i2;
    p1[t] = p[i1] * inv;
    p2[t] = p[i2] * inv;
    e1s[n] = (unsigned char)i1;
    e2s[n] = (unsigned char)i2;
  }
  __syncthreads();

  // phase 2: local counts for entries p = 4*tid .. 4*tid+3 (p = k*2048+n)
  int cnt[Ee] = {0, 0, 0, 0, 0, 0, 0, 0};
  int eloc[4];
#pragma unroll
  for (int i = 0; i < 4; ++i) {
    const int p = tid * 4 + i;
    const int e = (p >> 11) ? (int)e2s[p & 2047] : (int)e1s[p & 2047];
    eloc[i] = e;
    cnt[e]++;
  }
#pragma unroll
  for (int e = 0; e < Ee; ++e) cnts[tid][e] = cnt[e];
  __syncthreads();

  // phase 3: per-expert exclusive prefix over the 1024 thread-chunks
  const int wv = tid >> 6, ln = tid & 63;
  if (wv < 8) {
    int loc[16];
    int s = 0;
#pragma unroll
    for (int i = 0; i < 16; ++i) {
      loc[i] = cnts[ln * 16 + i][wv];
      s += loc[i];
    }
    int x = s;
#pragma unroll
    for (int off = 1; off < 64; off <<= 1) {
      int y = __shfl_up(x, off, 64);
      if (ln >= off) x += y;
    }
    int run = x - s;  // exclusive prefix of this lane's 16-chunk
#pragma unroll
    for (int i = 0; i < 16; ++i) {
      int tmp = loc[i];
      cnts[ln * 16 + i][wv] = run;
      run += tmp;
    }
  }
  __syncthreads();

  // phase 4: assign priorities in order
  int base[Ee];
#pragma unroll
  for (int e = 0; e < Ee; ++e) base[e] = cnts[tid][e];
#pragma unroll
  for (int i = 0; i < 4; ++i) {
    prios[b * 4096 + tid * 4 + i] = base[eloc[i]]++;
  }
}

// ---------------- branchless single-pass zero+scatter (one block/token) -----
__global__ __launch_bounds__(256) void zscatter_kernel(const int* __restrict__ idx1,
                                                       const int* __restrict__ idx2,
                                                       const float* __restrict__ p1,
                                                       const float* __restrict__ p2,
                                                       const int* __restrict__ prios,
                                                       float* __restrict__ out, int cap) {
  const int t = blockIdx.x;       // token 0..Mm-1
  const int ec = Ee * cap;        // 5120
  const int b = t >> 11;
  const int n = t & (Nn - 1);
  const int e1 = idx1[t], e2 = idx2[t];
  const int q1 = prios[b * 2 * Nn + n];
  const int q2 = prios[b * 2 * Nn + Nn + n];
  const float v1 = p1[t], v2 = p2[t];
  const int d1 = (q1 < cap) ? e1 * cap + q1 : -1;
  const int d2 = (q2 < cap) ? e2 * cap + q2 : -1;
  float4* o1 = (float4*)(out + (size_t)t * ec);             // dispatch slice
  float4* o2 = (float4*)(out + (size_t)(Mm + t) * ec);      // combine slice
  const int n4 = ec / 4;  // 1280
  for (int i = threadIdx.x; i < n4; i += 256) {
    const int base = i * 4;
    float4 dv, cv;
    dv.x = (d1 == base + 0 || d2 == base + 0) ? 1.f : 0.f;
    dv.y = (d1 == base + 1 || d2 == base + 1) ? 1.f : 0.f;
    dv.z = (d1 == base + 2 || d2 == base + 2) ? 1.f : 0.f;
    dv.w = (d1 == base + 3 || d2 == base + 3) ? 1.f : 0.f;
    cv.x = (d1 == base + 0) ? v1 : ((d2 == base + 0) ? v2 : 0.f);
    cv.y = (d1 == base + 1) ? v1 : ((d2 == base + 1) ? v2 : 0.f);
    cv.z = (d1 == base + 2) ? v1 : ((d2 == base + 2) ? v2 : 0.f);
    cv.w = (d1 == base + 3) ? v1 : ((d2 == base + 3) ? v2 : 0.f);
    o1[i] = dv;
    o2[i] = cv;
  }
}

extern "C" void kernel_launch(void* const* d_in, const int* in_sizes, int n_in,
                              void* d_out, int out_size, void* d_ws, size_t ws_size,
                              hipStream_t stream) {
  const float* X = (const float*)d_in[0];
  const float* W = (const float*)d_in[1];
  float* out = (float*)d_out;
  const int cap = out_size / (2 * Bb * Nn * Ee);  // 640

  char* ws = (char*)d_ws;
  _Float16* WT = (_Float16*)ws;                    // 32 MB tiled hi/lo W^T
  float* partial = (float*)(ws + 33554432ull);     // Mm*64 f32 = 2 MB
  int* idx1 = (int*)(ws + 35651584ull);
  int* idx2 = idx1 + Mm;
  float* p1 = (float*)(idx2 + Mm);
  float* p2 = p1 + Mm;
  int* prios = (int*)(p2 + Mm);

  // XT (64 MB, tiled hi/lo X) lives in d_out as scratch: consumed by gemm_mfma
  // and then fully overwritten by zscatter_kernel (stream-ordered).
  _Float16* XT = (_Float16*)d_out;

  prep_kernel<<<6144, 256, 0, stream>>>(W, WT, X, XT);
  gemm_mfma<<<512, 512, 0, stream>>>(XT, WT, partial);
  route_scan<<<Bb, 1024, 0, stream>>>(partial, idx1, idx2, p1, p2, prios);
  zscatter_kernel<<<Mm, 256, 0, stream>>>(idx1, idx2, p1, p2, prios, out, cap);
}